// Round 7
// baseline (305.244 us; speedup 1.0000x reference)
//
#include <hip/hip_runtime.h>
#include <hip/hip_bf16.h>

#define EPS_BN 1e-5f
#define DW_THRESH 4.0f
#define PW_THRESH 0.001f

// Problem dims (fixed by the reference)
#define BATCH 32
#define CIN   256
#define COUT  512
#define HIN   56
#define WIN   56
#define HOUT  54
#define WOUT  54
#define NPIX  (HOUT*WOUT)     // 2916
#define XPIX  (HIN*WIN)       // 3136
#define PPT   12              // pixels per thread in slow pw path

#define MAPS_DW 4             // (b,c) maps per block  (64 blocks/batch)
#define MAPS_PW 8             // o maps per block      (same 64 blocks/batch)
#define BLK_PER_B 64          // blocks per batch
// grid = 32 * 64 = 2048 blocks

// native clang vector type — accepted by __builtin_nontemporal_{load,store}
typedef float floatx4 __attribute__((ext_vector_type(4)));

// ---------------------------------------------------------------------------
// Kernel 0: zero the per-batch packed counters (replay-safe: d_ws is poisoned
// once, never re-poisoned between graph replays, so reset every execution).
// ---------------------------------------------------------------------------
__global__ void init_kernel(int* __restrict__ bstate) {
    if (threadIdx.x < BATCH) bstate[threadIdx.x] = 0;
}

// ---------------------------------------------------------------------------
// One (b,c) map pass: conv 3x3 + bias + BN + ReLU over this thread's
// 4-col x 3-row band. Returns the thread-local max. STORE=true also writes y.
// ---------------------------------------------------------------------------
template<bool STORE>
__device__ inline float dw_map(const float* __restrict__ xp,
                               const float* __restrict__ w,
                               float scale, float shift,
                               int g, int r0, float* __restrict__ yp)
{
    const int col0 = 4 * g;
    const int col1 = (g == 13) ? 48 : col0 + 4;  // clamped; extras only feed masked px

    floatx4 rowA[5], rowB[5];
#pragma unroll
    for (int j = 0; j < 5; ++j) {
        rowA[j] = *(const floatx4*)(xp + (r0 + j) * WIN + col0);
        rowB[j] = *(const floatx4*)(xp + (r0 + j) * WIN + col1);
    }

    float mx = 0.f;
#pragma unroll
    for (int i = 0; i < 3; ++i) {
        const float a0[6] = {rowA[i].x,   rowA[i].y,   rowA[i].z,   rowA[i].w,   rowB[i].x,   rowB[i].y};
        const float a1[6] = {rowA[i+1].x, rowA[i+1].y, rowA[i+1].z, rowA[i+1].w, rowB[i+1].x, rowB[i+1].y};
        const float a2[6] = {rowA[i+2].x, rowA[i+2].y, rowA[i+2].z, rowA[i+2].w, rowB[i+2].x, rowB[i+2].y};
#pragma unroll
        for (int p = 0; p < 4; ++p) {
            float acc;
            acc = a0[p] * w[0];
            acc = fmaf(a0[p + 1], w[1], acc);
            acc = fmaf(a0[p + 2], w[2], acc);
            acc = fmaf(a1[p],     w[3], acc);
            acc = fmaf(a1[p + 1], w[4], acc);
            acc = fmaf(a1[p + 2], w[5], acc);
            acc = fmaf(a2[p],     w[6], acc);
            acc = fmaf(a2[p + 1], w[7], acc);
            acc = fmaf(a2[p + 2], w[8], acc);
            float v = fmaf(acc, scale, shift);
            v = fmaxf(v, 0.f);               // relu -> v >= 0, max == maxabs
            const int col = col0 + p;
            if (col < WOUT) {
                mx = fmaxf(mx, v);
                if (STORE) yp[(r0 + i) * WOUT + col] = v;
            }
        }
    }
    return mx;
}

// ---------------------------------------------------------------------------
// Fused kernel: block (b, j) does
//   phase 1: dw max-pass for maps m = b*CIN + 4j .. +3 (y stored only on the
//            statistically-dead survive path)
//   sync:    packed release-atomicAdd{completed|survivors} on bstate[b];
//            tid0 acquire-spins until all 64 blocks of batch b reported
//   phase 2: pw for o = 8j .. 8j+7 of batch b (fast path: uniform nt stores)
// Deadlock-free: each batch's 64 blocks are contiguous in dispatch order and
// only depend on each other; any >=64-block resident window always contains a
// completable batch.
// ---------------------------------------------------------------------------
__global__ __launch_bounds__(256) void fused_kernel(
    const float* __restrict__ x,
    const float* __restrict__ dw_w, const float* __restrict__ dw_b,
    const float* __restrict__ dw_g, const float* __restrict__ dw_be,
    const float* __restrict__ dw_mean, const float* __restrict__ dw_var,
    const float* __restrict__ pw_w, const float* __restrict__ pw_b,
    const float* __restrict__ pw_g, const float* __restrict__ pw_be,
    const float* __restrict__ pw_mean, const float* __restrict__ pw_var,
    float* __restrict__ y, float* __restrict__ maxv, int* __restrict__ bstate,
    float* __restrict__ out)
{
    const int blk = blockIdx.x;
    const int b   = blk >> 6;          // batch
    const int j   = blk & (BLK_PER_B - 1);
    const int tid = threadIdx.x;

    const int g    = tid % 14;         // column group: output cols 4g..4g+3
    const int band = tid / 14;         // row band: output rows 3*band..3*band+2
    const bool active = (tid < 252);   // 14*18 = 252 working threads
    const int r0 = band * 3;

    __shared__ float swave[4][MAPS_DW];
    __shared__ int   ssurv;

    const int m0 = b * CIN + j * MAPS_DW;

    // ---------------- phase 1: depthwise max pass ----------------
    float wreg[MAPS_DW][9];
    float scl[MAPS_DW], shf[MAPS_DW];

#pragma unroll
    for (int k = 0; k < MAPS_DW; ++k) {
        const int c = (m0 + k) & (CIN - 1);
#pragma unroll
        for (int q = 0; q < 9; ++q) wreg[k][q] = dw_w[c * 9 + q];
        scl[k] = dw_g[c] * rsqrtf(dw_var[c] + EPS_BN);
        shf[k] = dw_be[c] - dw_mean[c] * scl[k] + dw_b[c] * scl[k];

        float mx = 0.f;
        if (active) {
            const float* xp = x + (size_t)(m0 + k) * XPIX;
            mx = dw_map<false>(xp, wreg[k], scl[k], shf[k], g, r0, nullptr);
        }
#pragma unroll
        for (int off = 32; off > 0; off >>= 1)
            mx = fmaxf(mx, __shfl_xor(mx, off));
        if ((tid & 63) == 0) swave[tid >> 6][k] = mx;
    }
    __syncthreads();

    float bmk[MAPS_DW];
#pragma unroll
    for (int k = 0; k < MAPS_DW; ++k)
        bmk[k] = fmaxf(fmaxf(swave[0][k], swave[1][k]),
                       fmaxf(swave[2][k], swave[3][k]));

    if (tid < MAPS_DW) maxv[m0 + tid] = bmk[tid];

    // statistically-dead survive path: recompute and store the y map
#pragma unroll
    for (int k = 0; k < MAPS_DW; ++k) {
        if (bmk[k] >= DW_THRESH && active) {
            const float* xp = x + (size_t)(m0 + k) * XPIX;
            float* yp = y + (size_t)(m0 + k) * NPIX;
            (void)dw_map<true>(xp, wreg[k], scl[k], shf[k], g, r0, yp);
        }
    }
    __syncthreads();   // all y/maxv stores issued before the release below

    // ---------------- handshake ----------------
    if (tid == 0) {
        __threadfence();
        int surv = 0;
#pragma unroll
        for (int k = 0; k < MAPS_DW; ++k) surv += (bmk[k] >= DW_THRESH) ? 1 : 0;
        __hip_atomic_fetch_add(&bstate[b], (1 << 16) | surv,
                               __ATOMIC_RELEASE, __HIP_MEMORY_SCOPE_AGENT);
        int v = __hip_atomic_load(&bstate[b], __ATOMIC_ACQUIRE, __HIP_MEMORY_SCOPE_AGENT);
        while ((v >> 16) < BLK_PER_B) {
            __builtin_amdgcn_s_sleep(2);
            v = __hip_atomic_load(&bstate[b], __ATOMIC_ACQUIRE, __HIP_MEMORY_SCOPE_AGENT);
        }
        ssurv = v & 0xFFFF;
    }
    __syncthreads();
    const int surv_total = ssurv;

    // ---------------- phase 2: pointwise ----------------
    const int o0 = j * MAPS_PW;

    if (surv_total == 0) {
        // acc == 0 everywhere: v = relu(shift_o), uniform over each map.
#pragma unroll
        for (int k = 0; k < MAPS_PW; ++k) {
            const int o = o0 + k;
            const float scale = pw_g[o] * rsqrtf(pw_var[o] + EPS_BN);
            const float shift = pw_be[o] - pw_mean[o] * scale + pw_b[o] * scale;
            float v = shift > 0.f ? shift : 0.f;
            const float val = (v >= PW_THRESH) ? v : 0.f;
            floatx4* op = (floatx4*)(out + (size_t)(b * COUT + o) * NPIX);  // 729 f4
            floatx4 f;
            f.x = val; f.y = val; f.z = val; f.w = val;
#pragma unroll
            for (int jj = 0; jj < 3; ++jj) {
                const int idx = tid + jj * 256;
                if (idx < NPIX / 4) __builtin_nontemporal_store(f, &op[idx]);
            }
        }
        return;
    }

    // ---- generic path (some channels survived; statistically dead) ----
    __shared__ int   sflag[CIN];
    __shared__ float sred[256];

    {
        const int lane = tid & 63;
        if (tid < 64) {
            const floatx4 mv = *(const floatx4*)(maxv + (size_t)b * CIN + 4 * lane);
            sflag[4 * lane + 0] = mv.x >= DW_THRESH;
            sflag[4 * lane + 1] = mv.y >= DW_THRESH;
            sflag[4 * lane + 2] = mv.z >= DW_THRESH;
            sflag[4 * lane + 3] = mv.w >= DW_THRESH;
        }
    }
    __syncthreads();

    for (int k = 0; k < MAPS_PW; ++k) {
        const int o = o0 + k;
        const float scale = pw_g[o] * rsqrtf(pw_var[o] + EPS_BN);
        const float shift = pw_be[o] - pw_mean[o] * scale + pw_b[o] * scale;

        float acc[PPT];
#pragma unroll
        for (int jj = 0; jj < PPT; ++jj) acc[jj] = 0.f;

        const float* wrow = pw_w + (size_t)o * CIN;
        for (int c = 0; c < CIN; ++c) {
            if (sflag[c]) {                      // block-uniform branch
                const float wv = wrow[c];
                const float* yp = y + (size_t)(b * CIN + c) * NPIX;
#pragma unroll
                for (int jj = 0; jj < PPT; ++jj) {
                    const int idx = tid + jj * 256;
                    if (idx < NPIX) acc[jj] = fmaf(yp[idx], wv, acc[jj]);
                }
            }
        }

        float r[PPT];
        float mx = 0.f;
#pragma unroll
        for (int jj = 0; jj < PPT; ++jj) {
            float v = fmaf(acc[jj], scale, shift);
            v = v > 0.f ? v : 0.f;
            r[jj] = v;
            mx = fmaxf(mx, v);
        }

        __syncthreads();          // protect sred reuse across k
        sred[tid] = mx;
        __syncthreads();
#pragma unroll
        for (int s = 128; s > 0; s >>= 1) {
            if (tid < s) sred[tid] = fmaxf(sred[tid], sred[tid + s]);
            __syncthreads();
        }
        const float bm = sred[0];
        const bool keep = (bm >= PW_THRESH);

        float* op = out + (size_t)(b * COUT + o) * NPIX;
#pragma unroll
        for (int jj = 0; jj < PPT; ++jj) {
            const int idx = tid + jj * 256;
            if (idx < NPIX) op[idx] = keep ? r[jj] : 0.f;
        }
    }
}

// ---------------------------------------------------------------------------
extern "C" void kernel_launch(void* const* d_in, const int* in_sizes, int n_in,
                              void* d_out, int out_size, void* d_ws, size_t ws_size,
                              hipStream_t stream) {
    const float* x       = (const float*)d_in[0];
    const float* dw_w    = (const float*)d_in[1];
    const float* dw_b    = (const float*)d_in[2];
    const float* dw_g    = (const float*)d_in[3];
    const float* dw_be   = (const float*)d_in[4];
    const float* dw_mean = (const float*)d_in[5];
    const float* dw_var  = (const float*)d_in[6];
    const float* pw_w    = (const float*)d_in[7];
    const float* pw_b    = (const float*)d_in[8];
    const float* pw_g    = (const float*)d_in[9];
    const float* pw_be   = (const float*)d_in[10];
    const float* pw_mean = (const float*)d_in[11];
    const float* pw_var  = (const float*)d_in[12];

    float* out = (float*)d_out;

    // workspace layout: y (B*CIN*NPIX f32), maxv (B*CIN f32), bstate (B int)
    float* y    = (float*)d_ws;
    float* maxv = (float*)((char*)d_ws + (size_t)BATCH * CIN * NPIX * sizeof(float));
    int*  bstate = (int*)(maxv + (size_t)BATCH * CIN);

    hipLaunchKernelGGL(init_kernel, dim3(1), dim3(64), 0, stream, bstate);

    dim3 grid(BATCH * BLK_PER_B);   // 2048 blocks
    hipLaunchKernelGGL(fused_kernel, grid, dim3(256), 0, stream,
                       x, dw_w, dw_b, dw_g, dw_be, dw_mean, dw_var,
                       pw_w, pw_b, pw_g, pw_be, pw_mean, pw_var,
                       y, maxv, bstate, out);
}

// Round 8
// 47.641 us; speedup vs baseline: 6.4071x; 6.4071x over previous
//
#include <hip/hip_runtime.h>
#include <hip/hip_bf16.h>

#define EPS_BN 1e-5f
#define DW_THRESH 4.0f
#define PW_THRESH 0.001f

// Problem dims (fixed by the reference)
#define BATCH 32
#define CIN   256
#define COUT  512
#define HIN   56
#define WIN   56
#define HOUT  54
#define WOUT  54
#define NPIX  (HOUT*WOUT)     // 2916
#define XPIX  (HIN*WIN)       // 3136
#define PPT   12              // pixels per thread in fixup generic path

// native clang vector type — accepted by __builtin_nontemporal_{load,store}
typedef float floatx4 __attribute__((ext_vector_type(4)));

// ---------------------------------------------------------------------------
// Kernel 1: one block per (b,c) map.
//  - depthwise 3x3 + bias + BN + ReLU, per-map max -> maxv[b*CIN+c]
//  - y written only on the (statistically dead) survive path
//  - then SPECULATIVELY writes out[b, 2c] and out[b, 2c+1] with the
//    zero-survivor uniform value cut(relu(pshift_o)) via nontemporal stores.
//    If any channel of batch b survives, the fixup kernel rewrites batch b.
// The read stream (x) and write stream (out) overlap across the 32
// block-generations per CU — no cross-block synchronization anywhere.
// ---------------------------------------------------------------------------
__global__ __launch_bounds__(256) void dwspec_kernel(
    const float* __restrict__ x,
    const float* __restrict__ dw_w, const float* __restrict__ dw_b,
    const float* __restrict__ dw_g, const float* __restrict__ dw_be,
    const float* __restrict__ dw_mean, const float* __restrict__ dw_var,
    const float* __restrict__ pw_w, const float* __restrict__ pw_b,
    const float* __restrict__ pw_g, const float* __restrict__ pw_be,
    const float* __restrict__ pw_mean, const float* __restrict__ pw_var,
    float* __restrict__ y, float* __restrict__ maxv,
    float* __restrict__ out)
{
    const int blk = blockIdx.x;        // == map index m = b*CIN + c
    const int b   = blk >> 8;
    const int c   = blk & (CIN - 1);
    const int tid = threadIdx.x;

    const int g    = tid % 14;         // column group: output cols 4g..4g+3
    const int band = tid / 14;         // row band: output rows 3*band..+2
    const bool active = (tid < 252);   // 14*18 = 252 working threads
    const int r0 = band * 3;

    __shared__ float swave[4];

    // ---- depthwise params ----
    float w[9];
#pragma unroll
    for (int k = 0; k < 9; ++k) w[k] = dw_w[c * 9 + k];
    const float scale = dw_g[c] * rsqrtf(dw_var[c] + EPS_BN);
    const float shift = dw_be[c] - dw_mean[c] * scale + dw_b[c] * scale;

    // ---- depthwise conv + max ----
    float r[3][4];
    float mx = 0.f;
    if (active) {
        const float* xp = x + (size_t)blk * XPIX;
        const int col0 = 4 * g;
        const int col1 = (g == 13) ? 48 : col0 + 4;  // clamped; extras masked

        floatx4 rowA[5], rowB[5];
#pragma unroll
        for (int j = 0; j < 5; ++j) {
            rowA[j] = *(const floatx4*)(xp + (r0 + j) * WIN + col0);
            rowB[j] = *(const floatx4*)(xp + (r0 + j) * WIN + col1);
        }

#pragma unroll
        for (int i = 0; i < 3; ++i) {
            const float a0[6] = {rowA[i].x,   rowA[i].y,   rowA[i].z,   rowA[i].w,   rowB[i].x,   rowB[i].y};
            const float a1[6] = {rowA[i+1].x, rowA[i+1].y, rowA[i+1].z, rowA[i+1].w, rowB[i+1].x, rowB[i+1].y};
            const float a2[6] = {rowA[i+2].x, rowA[i+2].y, rowA[i+2].z, rowA[i+2].w, rowB[i+2].x, rowB[i+2].y};
#pragma unroll
            for (int p = 0; p < 4; ++p) {
                float acc;
                acc = a0[p] * w[0];
                acc = fmaf(a0[p + 1], w[1], acc);
                acc = fmaf(a0[p + 2], w[2], acc);
                acc = fmaf(a1[p],     w[3], acc);
                acc = fmaf(a1[p + 1], w[4], acc);
                acc = fmaf(a1[p + 2], w[5], acc);
                acc = fmaf(a2[p],     w[6], acc);
                acc = fmaf(a2[p + 1], w[7], acc);
                acc = fmaf(a2[p + 2], w[8], acc);
                float v = fmaf(acc, scale, shift);
                v = fmaxf(v, 0.f);             // relu -> v >= 0, max == maxabs
                r[i][p] = v;
                if (4 * g + p < WOUT) mx = fmaxf(mx, v);
            }
        }
    }

    // wave-level max reduce, then 4-wave LDS combine
#pragma unroll
    for (int off = 32; off > 0; off >>= 1)
        mx = fmaxf(mx, __shfl_xor(mx, off));
    if ((tid & 63) == 0) swave[tid >> 6] = mx;
    __syncthreads();
    const float bm = fmaxf(fmaxf(swave[0], swave[1]), fmaxf(swave[2], swave[3]));

    if (tid == 0) maxv[blk] = bm;

    // statistically-dead survive path: store the y map
    if (bm >= DW_THRESH && active) {
        float* yp = y + (size_t)blk * NPIX;
#pragma unroll
        for (int i = 0; i < 3; ++i) {
#pragma unroll
            for (int p = 0; p < 4; ++p) {
                const int col = 4 * g + p;
                if (col < WOUT) yp[(r0 + i) * WOUT + col] = r[i][p];
            }
        }
    }

    // ---- speculative pointwise output: o = 2c, 2c+1 of batch b ----
#pragma unroll
    for (int k = 0; k < 2; ++k) {
        const int o = 2 * c + k;
        const float ps = pw_g[o] * rsqrtf(pw_var[o] + EPS_BN);
        const float pf = pw_be[o] - pw_mean[o] * ps + pw_b[o] * ps;
        float v = pf > 0.f ? pf : 0.f;
        const float val = (v >= PW_THRESH) ? v : 0.f;
        floatx4* op = (floatx4*)(out + (size_t)(b * COUT + o) * NPIX);  // 729 f4
        floatx4 f;
        f.x = val; f.y = val; f.z = val; f.w = val;
#pragma unroll
        for (int j = 0; j < 3; ++j) {
            const int idx = tid + j * 256;
            if (idx < NPIX / 4) __builtin_nontemporal_store(f, &op[idx]);
        }
    }
}

// ---------------------------------------------------------------------------
// Kernel 2: fixup. Grid (8, BATCH); block (q,b) owns o = 64q .. 64q+63.
// Fast exit (always, statistically): batch has no surviving channels.
// Otherwise: full generic pointwise for its 64 o-maps (slow, dead, correct).
// ---------------------------------------------------------------------------
__global__ __launch_bounds__(256) void fixup_kernel(
    const float* __restrict__ y, const float* __restrict__ maxv,
    const float* __restrict__ pw_w, const float* __restrict__ pw_b,
    const float* __restrict__ pw_g, const float* __restrict__ pw_be,
    const float* __restrict__ pw_mean, const float* __restrict__ pw_var,
    float* __restrict__ out)
{
    const int b   = blockIdx.y;
    const int o0  = blockIdx.x * 64;
    const int tid = threadIdx.x;
    const int lane = tid & 63;

    // lane l covers channels 4l..4l+3; every wave sees all 256 channels.
    const floatx4 mv = *(const floatx4*)(maxv + (size_t)b * CIN + 4 * lane);
    const bool anyl = (mv.x >= DW_THRESH) | (mv.y >= DW_THRESH) |
                      (mv.z >= DW_THRESH) | (mv.w >= DW_THRESH);
    if (!__any(anyl)) return;   // common case: speculative writes were correct

    // ---- generic path (statistically dead) ----
    __shared__ int   sflag[CIN];
    __shared__ float sred[256];

    if (tid < 64) {
        sflag[4 * tid + 0] = mv.x >= DW_THRESH;
        sflag[4 * tid + 1] = mv.y >= DW_THRESH;
        sflag[4 * tid + 2] = mv.z >= DW_THRESH;
        sflag[4 * tid + 3] = mv.w >= DW_THRESH;
    }
    __syncthreads();

    for (int k = 0; k < 64; ++k) {
        const int o = o0 + k;
        const float scale = pw_g[o] * rsqrtf(pw_var[o] + EPS_BN);
        const float shift = pw_be[o] - pw_mean[o] * scale + pw_b[o] * scale;

        float acc[PPT];
#pragma unroll
        for (int j = 0; j < PPT; ++j) acc[j] = 0.f;

        const float* wrow = pw_w + (size_t)o * CIN;
        for (int c = 0; c < CIN; ++c) {
            if (sflag[c]) {                      // block-uniform branch
                const float wv = wrow[c];
                const float* yp = y + (size_t)(b * CIN + c) * NPIX;
#pragma unroll
                for (int j = 0; j < PPT; ++j) {
                    const int idx = tid + j * 256;
                    if (idx < NPIX) acc[j] = fmaf(yp[idx], wv, acc[j]);
                }
            }
        }

        float r[PPT];
        float mx = 0.f;
#pragma unroll
        for (int j = 0; j < PPT; ++j) {
            float v = fmaf(acc[j], scale, shift);
            v = v > 0.f ? v : 0.f;
            r[j] = v;
            mx = fmaxf(mx, v);
        }

        __syncthreads();          // protect sred reuse across k
        sred[tid] = mx;
        __syncthreads();
#pragma unroll
        for (int s = 128; s > 0; s >>= 1) {
            if (tid < s) sred[tid] = fmaxf(sred[tid], sred[tid + s]);
            __syncthreads();
        }
        const float bm = sred[0];
        const bool keep = (bm >= PW_THRESH);

        float* op = out + (size_t)(b * COUT + o) * NPIX;
#pragma unroll
        for (int j = 0; j < PPT; ++j) {
            const int idx = tid + j * 256;
            if (idx < NPIX) op[idx] = keep ? r[j] : 0.f;
        }
    }
}

// ---------------------------------------------------------------------------
extern "C" void kernel_launch(void* const* d_in, const int* in_sizes, int n_in,
                              void* d_out, int out_size, void* d_ws, size_t ws_size,
                              hipStream_t stream) {
    const float* x       = (const float*)d_in[0];
    const float* dw_w    = (const float*)d_in[1];
    const float* dw_b    = (const float*)d_in[2];
    const float* dw_g    = (const float*)d_in[3];
    const float* dw_be   = (const float*)d_in[4];
    const float* dw_mean = (const float*)d_in[5];
    const float* dw_var  = (const float*)d_in[6];
    const float* pw_w    = (const float*)d_in[7];
    const float* pw_b    = (const float*)d_in[8];
    const float* pw_g    = (const float*)d_in[9];
    const float* pw_be   = (const float*)d_in[10];
    const float* pw_mean = (const float*)d_in[11];
    const float* pw_var  = (const float*)d_in[12];

    float* out = (float*)d_out;

    // workspace layout: y (B*CIN*NPIX f32), maxv (B*CIN f32)
    float* y    = (float*)d_ws;
    float* maxv = (float*)((char*)d_ws + (size_t)BATCH * CIN * NPIX * sizeof(float));

    dim3 grid1(BATCH * CIN);    // 8192 blocks, 1 per (b,c) map
    hipLaunchKernelGGL(dwspec_kernel, grid1, dim3(256), 0, stream,
                       x, dw_w, dw_b, dw_g, dw_be, dw_mean, dw_var,
                       pw_w, pw_b, pw_g, pw_be, pw_mean, pw_var,
                       y, maxv, out);

    dim3 grid2(COUT / 64, BATCH);   // 8 x 32 = 256 blocks
    hipLaunchKernelGGL(fixup_kernel, grid2, dim3(256), 0, stream,
                       y, maxv, pw_w, pw_b, pw_g, pw_be, pw_mean, pw_var, out);
}